// Round 1
// baseline (965.399 us; speedup 1.0000x reference)
//
#include <hip/hip_runtime.h>

#define MAXL 8
#define NC 81              // (MAXL+1)^2
#define NPAIR 1179648      // 3072*768/2
#define TOTW  2359296      // 3072*768
#define PI_F 3.14159265358979323846f

// ---------------- compile-time norm table ----------------
constexpr double cfact(int n){ double r=1.0; for(int i=2;i<=n;++i) r*=(double)i; return r; }
constexpr double csqrtd(double x){
  double r = (x > 1.0) ? x : 1.0;
  for (int i=0;i<200;++i) r = 0.5*(r + x/r);
  return r;
}
struct Norms { float v[NC]; };
constexpr Norms make_norms(){
  Norms t{};
  for (int l=0;l<=MAXL;++l)
    for (int m=-l;m<=l;++m){
      int am = m<0?-m:m;
      double nn = csqrtd((double)(2*l+1)*cfact(l-am)/cfact(l+am)/(4.0*3.14159265358979323846));
      t.v[l*l+l+m] = (float)nn;
    }
  return t;
}
__constant__ Norms g_norm = make_norms();

// ---------------- init: zero scale + accumulators ----------------
__global__ void k_init(unsigned* scaleBits, double* gacc){
  int t = threadIdx.x;
  if (t < 2) scaleBits[t] = 0u;
  if (t < 2*NC) gacc[t] = 0.0;
}

// ---------------- fuse weights, write (re,im), reduce max|z| ----------------
__global__ __launch_bounds__(256) void k_fuse_scale(const float* __restrict__ wfc,
    const float* __restrict__ wpr, float2* __restrict__ ctphi,
    unsigned* __restrict__ scaleBits, float imp0, float imp1){
  const int mat = blockIdx.y;
  const float2* w0 = (const float2*)(mat ? wpr : wfc);
  const float2* w1 = w0 + (TOTW/2);
  float2* dst = ctphi + (size_t)mat*NPAIR;
  float vmax = 0.0f;
  for (int i = blockIdx.x*blockDim.x + threadIdx.x; i < NPAIR; i += gridDim.x*blockDim.x){
    float2 a = w0[i], b = w1[i];
    float re = imp0*a.x + imp1*b.x;
    float im = imp0*a.y + imp1*b.y;
    dst[i] = make_float2(re, im);
    vmax = fmaxf(vmax, sqrtf(re*re + im*im));
  }
  for (int off=32; off; off>>=1) vmax = fmaxf(vmax, __shfl_down(vmax, off));
  if ((threadIdx.x & 63) == 0) atomicMax(scaleBits + mat, __float_as_uint(vmax));
}

// ---------------- map to sphere coords (in place) ----------------
__global__ __launch_bounds__(256) void k_sphere(float2* __restrict__ ctphi,
    const unsigned* __restrict__ scaleBits){
  const int mat = blockIdx.y;
  int i = blockIdx.x*blockDim.x + threadIdx.x;
  if (i >= NPAIR) return;
  float scale = __uint_as_float(scaleBits[mat]);
  float safe = scale > 0.0f ? scale : 1.0f;
  float2 z = ctphi[(size_t)mat*NPAIR + i];
  float pr, pi_;
  if (scale > 0.0f){
    float a = z.x/safe, b = z.y/safe;
    float den = coshf(2.0f*a) + cosf(2.0f*b);
    pr  = sinhf(2.0f*a)/den*0.95f;
    pi_ = sinf(2.0f*b)/den*0.95f;
  } else { pr = z.x; pi_ = z.y; }
  float r = sqrtf(pr*pr + pi_*pi_);
  float phi = atan2f(pi_, pr);
  float ct = cosf(2.0f*atanhf(fminf(r,0.99f))*PI_F/16.0f);
  ctphi[(size_t)mat*NPAIR + i] = make_float2(ct, phi);
}

// ---------------- coefficient reduction: acc[lm] = sum P*ang ----------------
__global__ __launch_bounds__(256) void k_coeff(const float2* __restrict__ ctphi,
                                               double* __restrict__ gacc){
  const int mat = blockIdx.y;
  const float2* src = ctphi + (size_t)mat*NPAIR;
  float acc[NC];
  #pragma unroll
  for (int v=0; v<NC; ++v) acc[v] = 0.0f;

  for (int i = blockIdx.x*blockDim.x + threadIdx.x; i < NPAIR; i += gridDim.x*blockDim.x){
    float2 cp = src[i];
    float X = cp.x;
    float sint = sqrtf(fmaxf(1.0f - X*X, 0.0f));
    float s1, c1; sincosf(cp.y, &s1, &c1);
    float cm = 1.0f, sm = 0.0f, pmm = 1.0f, fact = 1.0f;
    #pragma unroll
    for (int m=0; m<=MAXL; ++m){
      if (m > 0){
        float t = cm*c1 - sm*s1;
        sm = sm*c1 + cm*s1;
        cm = t;
        pmm = pmm * (-fact*sint);
        fact += 2.0f;
      }
      float p0 = pmm;
      acc[m*m + 2*m] += p0*cm;
      if (m > 0) acc[m*m] += p0*sm;
      if (m < MAXL){
        float p1 = X*(float)(2*m+1)*p0;
        acc[(m+1)*(m+1) + (m+1) + m] += p1*cm;
        if (m > 0) acc[(m+1)*(m+1) + 1] += p1*sm;
        #pragma unroll
        for (int l=m+2; l<=MAXL; ++l){
          float pn = ((float)(2*l-1)*X*p1 - (float)(l+m-1)*p0) * (1.0f/(float)(l-m));
          p0 = p1; p1 = pn;
          acc[l*l + l + m] += p1*cm;
          if (m > 0) acc[l*l + l - m] += p1*sm;
        }
      }
    }
  }

  __shared__ double red[4][NC];
  int lane = threadIdx.x & 63, wv = threadIdx.x >> 6;
  #pragma unroll
  for (int v=0; v<NC; ++v){
    double d = (double)acc[v];
    for (int off=32; off; off>>=1) d += __shfl_down(d, off);
    if (lane == 0) red[wv][v] = d;
  }
  __syncthreads();
  for (int v = threadIdx.x; v < NC; v += blockDim.x){
    double s = red[0][v] + red[1][v] + red[2][v] + red[3][v];
    unsafeAtomicAdd(gacc + mat*NC + v, s);
  }
}

// ---------------- compress (serial, tiny) ----------------
__global__ void k_compress(const double* __restrict__ gacc, float* __restrict__ cfin){
  if (threadIdx.x != 0) return;
  int mat = blockIdx.x;
  float c[NC], mg[NC]; int order[NC]; int rank[NC]; float e[NC];
  for (int v=0; v<NC; ++v){
    double m_ = (double)g_norm.v[v] * gacc[mat*NC + v] / (double)NPAIR;
    c[v] = (float)m_;
    mg[v] = fabsf(c[v]);
    order[v] = v;
  }
  // stable insertion sort, descending by magnitude (matches argsort(-mag))
  for (int k=1; k<NC; ++k){
    int ov = order[k]; float mv = mg[ov];
    int j = k-1;
    while (j >= 0 && mg[order[j]] < mv){ order[j+1] = order[j]; --j; }
    order[j+1] = ov;
  }
  float run = 0.0f;
  for (int k=0; k<NC; ++k){ float m_ = mg[order[k]]; run += m_*m_; e[k] = run; }
  float tot = e[NC-1];
  int kc;
  if (tot > 0.0f){
    float den = fmaxf(tot, 1e-30f);
    int cnt = 0;
    for (int k=0; k<NC; ++k) cnt += (e[k]/den <= 0.9999f) ? 1 : 0;
    kc = cnt + 1;
  } else kc = NC;
  if (kc < NC/2) kc = NC/2;  // 40
  for (int k=0; k<NC; ++k) rank[order[k]] = k;
  for (int v=0; v<NC; ++v){
    float cv = (rank[v] < kc) ? c[v] : 0.0f;
    if (fabsf(cv) <= 1e-10f) cv = 0.0f;   // inverse's |c|>1e-10 mask folded in
    cfin[mat*NC + v] = cv;
  }
}

// ---------------- inverse transform -> compact B1 (1536x384), B2 (768x1536) ----------------
__global__ __launch_bounds__(256) void k_inverse(const float* __restrict__ cfin,
    const unsigned* __restrict__ scaleBits, float* __restrict__ B1, float* __restrict__ B2){
  __shared__ float cA[NC], cB[NC], sc[2];
  if (threadIdx.x < NC){ cA[threadIdx.x] = cfin[threadIdx.x]; cB[threadIdx.x] = cfin[NC + threadIdx.x]; }
  if (threadIdx.x < 2) sc[threadIdx.x] = __uint_as_float(scaleBits[threadIdx.x]);
  __syncthreads();
  int j = blockIdx.x*blockDim.x + threadIdx.x;
  if (j >= NPAIR) return;

  float jf = (float)j;
  float r = fminf((jf + 0.5f) / 1179648.0f * 0.95f, 0.95f);
  // replicate reference fp32 op order exactly: ((2pi * i) * GOLDEN) mod 1
  float theta = fmodf((6.28318530717958647692f * jf) * 0.618033988749f, 1.0f);
  float phi = theta;                            // atan2(r sin t, r cos t) == t for t in [0,1)
  float X = cosf(2.0f*atanhf(fminf(r, 0.99f))*PI_F/16.0f);
  float sint = sqrtf(fmaxf(1.0f - X*X, 0.0f));
  float s1, c1; sincosf(phi, &s1, &c1);

  float ra = 0.0f, rb = 0.0f;
  float cm = 1.0f, sm = 0.0f, pmm = 1.0f, fact = 1.0f;

  auto emit = [&](int l, int m, float P){
    int ip = l*l + l + m;
    float y = g_norm.v[ip] * P;
    float yc = y*cm;
    ra += cA[ip]*yc; rb += cB[ip]*yc;
    if (m > 0){
      int in_ = l*l + l - m;
      float ys = y*sm;
      ra += cA[in_]*ys; rb += cB[in_]*ys;
    }
  };

  #pragma unroll
  for (int m=0; m<=MAXL; ++m){
    if (m > 0){
      float t = cm*c1 - sm*s1;
      sm = sm*c1 + cm*s1;
      cm = t;
      pmm = pmm * (-fact*sint);
      fact += 2.0f;
    }
    float p0 = pmm;
    emit(m, m, p0);
    if (m < MAXL){
      float p1 = X*(float)(2*m+1)*p0;
      emit(m+1, m, p1);
      #pragma unroll
      for (int l=m+2; l<=MAXL; ++l){
        float pn = ((float)(2*l-1)*X*p1 - (float)(l+m-1)*p0) * (1.0f/(float)(l-m));
        p0 = p1; p1 = pn;
        emit(l, m, p1);
      }
    }
  }

  float sA = sc[0], sB = sc[1];
  B2[j] = (sB > 0.0f) ? rb*sB : rb;             // W_proj[d][2fc], flat j = d*1536+fc
  int q = j / 768, rem = j - q*768;
  if (rem < 384)                                // even rows of W_fc only
    B1[q*384 + rem] = (sA > 0.0f) ? ra*sA : ra; // W_fc[2fr][2dc], fr=q, dc=rem
}

// ---------------- gather even columns of x ----------------
__global__ void k_gather(const float* __restrict__ x, float* __restrict__ A1){
  int t = blockIdx.x*blockDim.x + threadIdx.x;
  if (t < 8192*384){
    int row = t/384, dc = t - row*384;
    A1[t] = x[(size_t)row*768 + dc*2];
  }
}

// ---------------- tiled fp32 GEMM (NT): C[M,N] = A[M,K] . B[N,K]^T + bias (opt gelu) --------
template<int ACT>
__global__ __launch_bounds__(256) void k_gemm(
    const float* __restrict__ A, const float* __restrict__ B,
    const float* __restrict__ bias, int bmul, int blen,
    float imp0, float imp1,
    float* __restrict__ C, int M, int N, int K)
{
  const int BM=64, BN=64, BK=16;
  __shared__ float As[BK][BM+4];
  __shared__ float Bs[BK][BN+4];
  const int tid = threadIdx.x;
  const int tx = tid & 15, ty = tid >> 4;
  const int bm = blockIdx.y*BM, bn = blockIdx.x*BN;
  const int lr = tid >> 2, lc4 = (tid & 3)*4;
  const float* Ap = A + (size_t)(bm+lr)*K + lc4;
  const float* Bp = B + (size_t)(bn+lr)*K + lc4;
  float acc[4][4] = {};

  for (int k0=0; k0<K; k0+=BK){
    float4 av = *(const float4*)(Ap + k0);
    float4 bv = *(const float4*)(Bp + k0);
    __syncthreads();
    As[lc4+0][lr]=av.x; As[lc4+1][lr]=av.y; As[lc4+2][lr]=av.z; As[lc4+3][lr]=av.w;
    Bs[lc4+0][lr]=bv.x; Bs[lc4+1][lr]=bv.y; Bs[lc4+2][lr]=bv.z; Bs[lc4+3][lr]=bv.w;
    __syncthreads();
    #pragma unroll
    for (int kk=0; kk<BK; ++kk){
      float4 a = *(const float4*)&As[kk][ty*4];
      float4 b = *(const float4*)&Bs[kk][tx*4];
      const float av2[4] = {a.x,a.y,a.z,a.w};
      const float bv2[4] = {b.x,b.y,b.z,b.w};
      #pragma unroll
      for (int i=0;i<4;++i)
        #pragma unroll
        for (int jj=0;jj<4;++jj)
          acc[i][jj] = fmaf(av2[i], bv2[jj], acc[i][jj]);
    }
  }

  #pragma unroll
  for (int i=0;i<4;++i){
    int row = bm + ty*4 + i;
    float4 o;
    float* op = (float*)&o;
    #pragma unroll
    for (int jj=0;jj<4;++jj){
      int col = bn + tx*4 + jj;
      float bvv = imp0*bias[bmul*col] + imp1*bias[blen + bmul*col];
      float v = acc[i][jj] + bvv;
      if (ACT) v = 0.5f*v*(1.0f + erff(v*0.70710678118654752440f));
      op[jj] = v;
    }
    *(float4*)(C + (size_t)row*N + bn + tx*4) = o;
  }
}

// ---------------- launch ----------------
extern "C" void kernel_launch(void* const* d_in, const int* in_sizes, int n_in,
                              void* d_out, int out_size, void* d_ws, size_t ws_size,
                              hipStream_t stream){
  const float* x   = (const float*)d_in[0];
  const float* wfc = (const float*)d_in[1];
  const float* wpr = (const float*)d_in[2];
  const float* bfc = (const float*)d_in[3];
  const float* bpr = (const float*)d_in[4];
  float* out = (float*)d_out;

  char* ws = (char*)d_ws;
  size_t off = 0;
  auto alloc = [&](size_t bytes){ void* p = ws + off; off = (off + bytes + 255) & ~(size_t)255; return p; };

  float2* ctphi      = (float2*)  alloc(2*(size_t)NPAIR*sizeof(float2));   // fused pairs, then (cos_t,phi)
  unsigned* scaleBits= (unsigned*)alloc(8);
  double* gacc       = (double*)  alloc(2*NC*sizeof(double));
  float* cfin        = (float*)   alloc(2*NC*sizeof(float));
  float* B1          = (float*)   alloc((size_t)1536*384*sizeof(float));
  float* B2          = (float*)   alloc((size_t)768*1536*sizeof(float));
  float* A1          = (float*)   alloc((size_t)8192*384*sizeof(float));
  float* H           = (float*)   alloc((size_t)8192*1536*sizeof(float));

  const float imp0 = (float)0.37754066879814546;   // softmax([0,0.5])
  const float imp1 = (float)0.62245933120185454;

  k_init<<<1,256,0,stream>>>(scaleBits, gacc);
  k_fuse_scale<<<dim3(1152,2),256,0,stream>>>(wfc, wpr, ctphi, scaleBits, imp0, imp1);
  k_sphere<<<dim3(4608,2),256,0,stream>>>(ctphi, scaleBits);
  k_coeff<<<dim3(512,2),256,0,stream>>>(ctphi, gacc);
  k_compress<<<2,64,0,stream>>>(gacc, cfin);
  k_inverse<<<4608,256,0,stream>>>(cfin, scaleBits, B1, B2);
  k_gather<<<12288,256,0,stream>>>(x, A1);
  // GEMM1: H[8192,1536] = gelu(A1 . B1^T + bias_fc[2*col])
  k_gemm<1><<<dim3(24,128),256,0,stream>>>(A1, B1, bfc, 2, 3072, imp0, imp1, H, 8192, 1536, 384);
  // GEMM2: out[8192,768] = H . B2^T + bias_proj[col]
  k_gemm<0><<<dim3(12,128),256,0,stream>>>(H, B2, bpr, 1, 768, imp0, imp1, out, 8192, 768, 1536);
}

// Round 2
// 661.626 us; speedup vs baseline: 1.4591x; 1.4591x over previous
//
#include <hip/hip_runtime.h>

#define MAXL 8
#define NC 81              // (MAXL+1)^2
#define NPAIR 1179648      // 3072*768/2
#define TOTW  2359296      // 3072*768
#define PI_F 3.14159265358979323846f

// ---------------- compile-time norm table ----------------
constexpr double cfact(int n){ double r=1.0; for(int i=2;i<=n;++i) r*=(double)i; return r; }
constexpr double csqrtd(double x){
  double r = (x > 1.0) ? x : 1.0;
  for (int i=0;i<200;++i) r = 0.5*(r + x/r);
  return r;
}
struct Norms { float v[NC]; };
constexpr Norms make_norms(){
  Norms t{};
  for (int l=0;l<=MAXL;++l)
    for (int m=-l;m<=l;++m){
      int am = m<0?-m:m;
      double nn = csqrtd((double)(2*l+1)*cfact(l-am)/cfact(l+am)/(4.0*3.14159265358979323846));
      t.v[l*l+l+m] = (float)nn;
    }
  return t;
}
__constant__ Norms g_norm = make_norms();

// ---------------- init: zero scale + accumulators ----------------
__global__ void k_init(unsigned* scaleBits, double* gacc){
  int t = threadIdx.x;
  if (t < 2) scaleBits[t] = 0u;
  if (t < 2*NC) gacc[t] = 0.0;
}

// ---------------- fuse weights, write (re,im), reduce max|z| ----------------
__global__ __launch_bounds__(256) void k_fuse_scale(const float* __restrict__ wfc,
    const float* __restrict__ wpr, float2* __restrict__ ctphi,
    unsigned* __restrict__ scaleBits, float imp0, float imp1){
  const int mat = blockIdx.y;
  const float2* w0 = (const float2*)(mat ? wpr : wfc);
  const float2* w1 = w0 + (TOTW/2);
  float2* dst = ctphi + (size_t)mat*NPAIR;
  float vmax = 0.0f;
  for (int i = blockIdx.x*blockDim.x + threadIdx.x; i < NPAIR; i += gridDim.x*blockDim.x){
    float2 a = w0[i], b = w1[i];
    float re = imp0*a.x + imp1*b.x;
    float im = imp0*a.y + imp1*b.y;
    dst[i] = make_float2(re, im);
    vmax = fmaxf(vmax, sqrtf(re*re + im*im));
  }
  for (int off=32; off; off>>=1) vmax = fmaxf(vmax, __shfl_down(vmax, off));
  if ((threadIdx.x & 63) == 0) atomicMax(scaleBits + mat, __float_as_uint(vmax));
}

// ---------------- map to sphere coords (in place) ----------------
__global__ __launch_bounds__(256) void k_sphere(float2* __restrict__ ctphi,
    const unsigned* __restrict__ scaleBits){
  const int mat = blockIdx.y;
  int i = blockIdx.x*blockDim.x + threadIdx.x;
  if (i >= NPAIR) return;
  float scale = __uint_as_float(scaleBits[mat]);
  float safe = scale > 0.0f ? scale : 1.0f;
  float2 z = ctphi[(size_t)mat*NPAIR + i];
  float pr, pi_;
  if (scale > 0.0f){
    float a = z.x/safe, b = z.y/safe;
    float den = coshf(2.0f*a) + cosf(2.0f*b);
    pr  = sinhf(2.0f*a)/den*0.95f;
    pi_ = sinf(2.0f*b)/den*0.95f;
  } else { pr = z.x; pi_ = z.y; }
  float r = sqrtf(pr*pr + pi_*pi_);
  float phi = atan2f(pi_, pr);
  float ct = cosf(2.0f*atanhf(fminf(r,0.99f))*PI_F/16.0f);
  ctphi[(size_t)mat*NPAIR + i] = make_float2(ct, phi);
}

// ---------------- coefficient reduction: acc[lm] = sum P*ang ----------------
__global__ __launch_bounds__(256) void k_coeff(const float2* __restrict__ ctphi,
                                               double* __restrict__ gacc){
  const int mat = blockIdx.y;
  const float2* src = ctphi + (size_t)mat*NPAIR;
  float acc[NC];
  #pragma unroll
  for (int v=0; v<NC; ++v) acc[v] = 0.0f;

  for (int i = blockIdx.x*blockDim.x + threadIdx.x; i < NPAIR; i += gridDim.x*blockDim.x){
    float2 cp = src[i];
    float X = cp.x;
    float sint = sqrtf(fmaxf(1.0f - X*X, 0.0f));
    float s1, c1; sincosf(cp.y, &s1, &c1);
    float cm = 1.0f, sm = 0.0f, pmm = 1.0f, fact = 1.0f;
    #pragma unroll
    for (int m=0; m<=MAXL; ++m){
      if (m > 0){
        float t = cm*c1 - sm*s1;
        sm = sm*c1 + cm*s1;
        cm = t;
        pmm = pmm * (-fact*sint);
        fact += 2.0f;
      }
      float p0 = pmm;
      acc[m*m + 2*m] += p0*cm;
      if (m > 0) acc[m*m] += p0*sm;
      if (m < MAXL){
        float p1 = X*(float)(2*m+1)*p0;
        acc[(m+1)*(m+1) + (m+1) + m] += p1*cm;
        if (m > 0) acc[(m+1)*(m+1) + 1] += p1*sm;
        #pragma unroll
        for (int l=m+2; l<=MAXL; ++l){
          float pn = ((float)(2*l-1)*X*p1 - (float)(l+m-1)*p0) * (1.0f/(float)(l-m));
          p0 = p1; p1 = pn;
          acc[l*l + l + m] += p1*cm;
          if (m > 0) acc[l*l + l - m] += p1*sm;
        }
      }
    }
  }

  __shared__ double red[4][NC];
  int lane = threadIdx.x & 63, wv = threadIdx.x >> 6;
  #pragma unroll
  for (int v=0; v<NC; ++v){
    double d = (double)acc[v];
    for (int off=32; off; off>>=1) d += __shfl_down(d, off);
    if (lane == 0) red[wv][v] = d;
  }
  __syncthreads();
  for (int v = threadIdx.x; v < NC; v += blockDim.x){
    double s = red[0][v] + red[1][v] + red[2][v] + red[3][v];
    unsafeAtomicAdd(gacc + mat*NC + v, s);
  }
}

// ---------------- compress: parallel (81 threads), all state in LDS/regs ----------------
// Exactly reproduces the serial semantics: stable descending argsort (rank by
// counting), sequential fp32 cumsum in rank order, kc threshold, |c|<=1e-10 mask.
__global__ __launch_bounds__(128) void k_compress(const double* __restrict__ gacc,
                                                  float* __restrict__ cfin){
  const int mat = blockIdx.x;
  const int v = threadIdx.x;
  __shared__ float mg[NC];
  __shared__ float smg2[NC];   // mg^2 scattered into rank order
  __shared__ int cnt_sh;

  float c = 0.0f, m = -1.0f;
  if (v < NC){
    double m_ = (double)g_norm.v[v] * gacc[mat*NC + v] / (double)NPAIR;
    c = (float)m_;
    m = fabsf(c);
    mg[v] = m;
  }
  if (v == 0) cnt_sh = 0;
  __syncthreads();

  int rank = 0;
  if (v < NC){
    #pragma unroll 1
    for (int u = 0; u < NC; ++u){
      float mu = mg[u];
      rank += (mu > m) || (mu == m && u < v);
    }
    smg2[rank] = m*m;
  }
  __syncthreads();

  // sequential fp32 cumsum in sorted order; grab e at my rank and the total
  float e_mine = 0.0f, tot = 0.0f;
  if (v < NC){
    float run = 0.0f;
    #pragma unroll 1
    for (int u = 0; u < NC; ++u){
      run += smg2[u];
      if (u == rank) e_mine = run;
    }
    tot = run;
    float den = fmaxf(tot, 1e-30f);
    if (tot > 0.0f && (e_mine / den <= 0.9999f)) atomicAdd(&cnt_sh, 1);
  }
  __syncthreads();

  if (v < NC){
    int kc = (tot > 0.0f) ? (cnt_sh + 1) : NC;
    if (kc < NC/2) kc = NC/2;   // 40
    float cv = (rank < kc) ? c : 0.0f;
    if (fabsf(cv) <= 1e-10f) cv = 0.0f;   // inverse's |c|>1e-10 mask folded in
    cfin[mat*NC + v] = cv;
  }
}

// ---------------- inverse transform -> compact B1 (1536x384), B2 (768x1536) ----------------
__global__ __launch_bounds__(256) void k_inverse(const float* __restrict__ cfin,
    const unsigned* __restrict__ scaleBits, float* __restrict__ B1, float* __restrict__ B2){
  __shared__ float cA[NC], cB[NC], sc[2];
  if (threadIdx.x < NC){ cA[threadIdx.x] = cfin[threadIdx.x]; cB[threadIdx.x] = cfin[NC + threadIdx.x]; }
  if (threadIdx.x < 2) sc[threadIdx.x] = __uint_as_float(scaleBits[threadIdx.x]);
  __syncthreads();
  int j = blockIdx.x*blockDim.x + threadIdx.x;
  if (j >= NPAIR) return;

  float jf = (float)j;
  float r = fminf((jf + 0.5f) / 1179648.0f * 0.95f, 0.95f);
  // replicate reference fp32 op order exactly: ((2pi * i) * GOLDEN) mod 1
  float theta = fmodf((6.28318530717958647692f * jf) * 0.618033988749f, 1.0f);
  float phi = theta;                            // atan2(r sin t, r cos t) == t for t in [0,1)
  float X = cosf(2.0f*atanhf(fminf(r, 0.99f))*PI_F/16.0f);
  float sint = sqrtf(fmaxf(1.0f - X*X, 0.0f));
  float s1, c1; sincosf(phi, &s1, &c1);

  float ra = 0.0f, rb = 0.0f;
  float cm = 1.0f, sm = 0.0f, pmm = 1.0f, fact = 1.0f;

  auto emit = [&](int l, int m, float P){
    int ip = l*l + l + m;
    float y = g_norm.v[ip] * P;
    float yc = y*cm;
    ra += cA[ip]*yc; rb += cB[ip]*yc;
    if (m > 0){
      int in_ = l*l + l - m;
      float ys = y*sm;
      ra += cA[in_]*ys; rb += cB[in_]*ys;
    }
  };

  #pragma unroll
  for (int m=0; m<=MAXL; ++m){
    if (m > 0){
      float t = cm*c1 - sm*s1;
      sm = sm*c1 + cm*s1;
      cm = t;
      pmm = pmm * (-fact*sint);
      fact += 2.0f;
    }
    float p0 = pmm;
    emit(m, m, p0);
    if (m < MAXL){
      float p1 = X*(float)(2*m+1)*p0;
      emit(m+1, m, p1);
      #pragma unroll
      for (int l=m+2; l<=MAXL; ++l){
        float pn = ((float)(2*l-1)*X*p1 - (float)(l+m-1)*p0) * (1.0f/(float)(l-m));
        p0 = p1; p1 = pn;
        emit(l, m, p1);
      }
    }
  }

  float sA = sc[0], sB = sc[1];
  B2[j] = (sB > 0.0f) ? rb*sB : rb;             // W_proj[d][2fc], flat j = d*1536+fc
  int q = j / 768, rem = j - q*768;
  if (rem < 384)                                // even rows of W_fc only
    B1[q*384 + rem] = (sA > 0.0f) ? ra*sA : ra; // W_fc[2fr][2dc], fr=q, dc=rem
}

// ---------------- gather even columns of x ----------------
__global__ void k_gather(const float* __restrict__ x, float* __restrict__ A1){
  int t = blockIdx.x*blockDim.x + threadIdx.x;
  if (t < 8192*384){
    int row = t/384, dc = t - row*384;
    A1[t] = x[(size_t)row*768 + dc*2];
  }
}

// ---------------- tiled fp32 GEMM (NT): C[M,N] = A[M,K] . B[N,K]^T + bias (opt gelu) --------
template<int ACT>
__global__ __launch_bounds__(256) void k_gemm(
    const float* __restrict__ A, const float* __restrict__ B,
    const float* __restrict__ bias, int bmul, int blen,
    float imp0, float imp1,
    float* __restrict__ C, int M, int N, int K)
{
  const int BM=64, BN=64, BK=16;
  __shared__ float As[BK][BM+4];
  __shared__ float Bs[BK][BN+4];
  const int tid = threadIdx.x;
  const int tx = tid & 15, ty = tid >> 4;
  const int bm = blockIdx.y*BM, bn = blockIdx.x*BN;
  const int lr = tid >> 2, lc4 = (tid & 3)*4;
  const float* Ap = A + (size_t)(bm+lr)*K + lc4;
  const float* Bp = B + (size_t)(bn+lr)*K + lc4;
  float acc[4][4] = {};

  for (int k0=0; k0<K; k0+=BK){
    float4 av = *(const float4*)(Ap + k0);
    float4 bv = *(const float4*)(Bp + k0);
    __syncthreads();
    As[lc4+0][lr]=av.x; As[lc4+1][lr]=av.y; As[lc4+2][lr]=av.z; As[lc4+3][lr]=av.w;
    Bs[lc4+0][lr]=bv.x; Bs[lc4+1][lr]=bv.y; Bs[lc4+2][lr]=bv.z; Bs[lc4+3][lr]=bv.w;
    __syncthreads();
    #pragma unroll
    for (int kk=0; kk<BK; ++kk){
      float4 a = *(const float4*)&As[kk][ty*4];
      float4 b = *(const float4*)&Bs[kk][tx*4];
      const float av2[4] = {a.x,a.y,a.z,a.w};
      const float bv2[4] = {b.x,b.y,b.z,b.w};
      #pragma unroll
      for (int i=0;i<4;++i)
        #pragma unroll
        for (int jj=0;jj<4;++jj)
          acc[i][jj] = fmaf(av2[i], bv2[jj], acc[i][jj]);
    }
  }

  #pragma unroll
  for (int i=0;i<4;++i){
    int row = bm + ty*4 + i;
    float4 o;
    float* op = (float*)&o;
    #pragma unroll
    for (int jj=0;jj<4;++jj){
      int col = bn + tx*4 + jj;
      float bvv = imp0*bias[bmul*col] + imp1*bias[blen + bmul*col];
      float v = acc[i][jj] + bvv;
      if (ACT) v = 0.5f*v*(1.0f + erff(v*0.70710678118654752440f));
      op[jj] = v;
    }
    *(float4*)(C + (size_t)row*N + bn + tx*4) = o;
  }
}

// ---------------- launch ----------------
extern "C" void kernel_launch(void* const* d_in, const int* in_sizes, int n_in,
                              void* d_out, int out_size, void* d_ws, size_t ws_size,
                              hipStream_t stream){
  const float* x   = (const float*)d_in[0];
  const float* wfc = (const float*)d_in[1];
  const float* wpr = (const float*)d_in[2];
  const float* bfc = (const float*)d_in[3];
  const float* bpr = (const float*)d_in[4];
  float* out = (float*)d_out;

  char* ws = (char*)d_ws;
  size_t off = 0;
  auto alloc = [&](size_t bytes){ void* p = ws + off; off = (off + bytes + 255) & ~(size_t)255; return p; };

  float2* ctphi      = (float2*)  alloc(2*(size_t)NPAIR*sizeof(float2));   // fused pairs, then (cos_t,phi)
  unsigned* scaleBits= (unsigned*)alloc(8);
  double* gacc       = (double*)  alloc(2*NC*sizeof(double));
  float* cfin        = (float*)   alloc(2*NC*sizeof(float));
  float* B1          = (float*)   alloc((size_t)1536*384*sizeof(float));
  float* B2          = (float*)   alloc((size_t)768*1536*sizeof(float));
  float* A1          = (float*)   alloc((size_t)8192*384*sizeof(float));
  float* H           = (float*)   alloc((size_t)8192*1536*sizeof(float));

  const float imp0 = (float)0.37754066879814546;   // softmax([0,0.5])
  const float imp1 = (float)0.62245933120185454;

  k_init<<<1,256,0,stream>>>(scaleBits, gacc);
  k_fuse_scale<<<dim3(1152,2),256,0,stream>>>(wfc, wpr, ctphi, scaleBits, imp0, imp1);
  k_sphere<<<dim3(4608,2),256,0,stream>>>(ctphi, scaleBits);
  k_coeff<<<dim3(512,2),256,0,stream>>>(ctphi, gacc);
  k_compress<<<2,128,0,stream>>>(gacc, cfin);
  k_inverse<<<4608,256,0,stream>>>(cfin, scaleBits, B1, B2);
  k_gather<<<12288,256,0,stream>>>(x, A1);
  // GEMM1: H[8192,1536] = gelu(A1 . B1^T + bias_fc[2*col])
  k_gemm<1><<<dim3(24,128),256,0,stream>>>(A1, B1, bfc, 2, 3072, imp0, imp1, H, 8192, 1536, 384);
  // GEMM2: out[8192,768] = H . B2^T + bias_proj[col]
  k_gemm<0><<<dim3(12,128),256,0,stream>>>(H, B2, bpr, 1, 768, imp0, imp1, out, 8192, 768, 1536);
}

// Round 3
// 322.934 us; speedup vs baseline: 2.9895x; 2.0488x over previous
//
#include <hip/hip_runtime.h>

#define MAXL 8
#define NC 81              // (MAXL+1)^2
#define NPAIR 1179648      // 3072*768/2
#define TOTW  2359296      // 3072*768
#define PI_F 3.14159265358979323846f

typedef __attribute__((ext_vector_type(8))) __bf16 bf16x8;
typedef __attribute__((ext_vector_type(4))) float f32x4;
typedef __attribute__((address_space(3))) void lds_void;
typedef const __attribute__((address_space(1))) void glb_void;

// ---------------- compile-time norm table ----------------
constexpr double cfact(int n){ double r=1.0; for(int i=2;i<=n;++i) r*=(double)i; return r; }
constexpr double csqrtd(double x){
  double r = (x > 1.0) ? x : 1.0;
  for (int i=0;i<200;++i) r = 0.5*(r + x/r);
  return r;
}
struct Norms { float v[NC]; };
constexpr Norms make_norms(){
  Norms t{};
  for (int l=0;l<=MAXL;++l)
    for (int m=-l;m<=l;++m){
      int am = m<0?-m:m;
      double nn = csqrtd((double)(2*l+1)*cfact(l-am)/cfact(l+am)/(4.0*3.14159265358979323846));
      t.v[l*l+l+m] = (float)nn;
    }
  return t;
}
__constant__ Norms g_norm = make_norms();

// ---------------- init: zero scale + accumulators ----------------
__global__ void k_init(unsigned* scaleBits, double* gacc){
  int t = threadIdx.x;
  if (t < 2) scaleBits[t] = 0u;
  if (t < 2*NC) gacc[t] = 0.0;
}

// ---------------- fuse weights, write (re,im), reduce max|z| ----------------
__global__ __launch_bounds__(256) void k_fuse_scale(const float* __restrict__ wfc,
    const float* __restrict__ wpr, float2* __restrict__ fused,
    unsigned* __restrict__ scaleBits, float imp0, float imp1){
  const int mat = blockIdx.y;
  const float2* w0 = (const float2*)(mat ? wpr : wfc);
  const float2* w1 = w0 + (TOTW/2);
  float2* dst = fused + (size_t)mat*NPAIR;
  float vmax = 0.0f;
  for (int i = blockIdx.x*blockDim.x + threadIdx.x; i < NPAIR; i += gridDim.x*blockDim.x){
    float2 a = w0[i], b = w1[i];
    float re = imp0*a.x + imp1*b.x;
    float im = imp0*a.y + imp1*b.y;
    dst[i] = make_float2(re, im);
    vmax = fmaxf(vmax, sqrtf(re*re + im*im));
  }
  for (int off=32; off; off>>=1) vmax = fmaxf(vmax, __shfl_down(vmax, off));
  if ((threadIdx.x & 63) == 0) atomicMax(scaleBits + mat, __float_as_uint(vmax));
}

// ---------------- coeff reduction with fused sphere mapping ----------------
__global__ __launch_bounds__(256) void k_coeff(const float2* __restrict__ fused,
                                               const unsigned* __restrict__ scaleBits,
                                               double* __restrict__ gacc){
  const int mat = blockIdx.y;
  const float2* src = fused + (size_t)mat*NPAIR;
  const float scale = __uint_as_float(scaleBits[mat]);
  const float safe = scale > 0.0f ? scale : 1.0f;
  const bool has = scale > 0.0f;

  float acc[NC];
  #pragma unroll
  for (int v=0; v<NC; ++v) acc[v] = 0.0f;

  for (int i = blockIdx.x*blockDim.x + threadIdx.x; i < NPAIR; i += gridDim.x*blockDim.x){
    float2 z = src[i];
    float pr, pi_;
    if (has){
      float a = z.x/safe, b = z.y/safe;
      float den = coshf(2.0f*a) + cosf(2.0f*b);
      pr  = sinhf(2.0f*a)/den*0.95f;
      pi_ = sinf(2.0f*b)/den*0.95f;
    } else { pr = z.x; pi_ = z.y; }
    float r = sqrtf(pr*pr + pi_*pi_);
    float phi = atan2f(pi_, pr);
    float X = cosf(2.0f*atanhf(fminf(r,0.99f))*PI_F/16.0f);

    float sint = sqrtf(fmaxf(1.0f - X*X, 0.0f));
    float s1, c1; sincosf(phi, &s1, &c1);
    float cm = 1.0f, sm = 0.0f, pmm = 1.0f, fact = 1.0f;
    #pragma unroll
    for (int m=0; m<=MAXL; ++m){
      if (m > 0){
        float t = cm*c1 - sm*s1;
        sm = sm*c1 + cm*s1;
        cm = t;
        pmm = pmm * (-fact*sint);
        fact += 2.0f;
      }
      float p0 = pmm;
      acc[m*m + 2*m] += p0*cm;
      if (m > 0) acc[m*m] += p0*sm;
      if (m < MAXL){
        float p1 = X*(float)(2*m+1)*p0;
        acc[(m+1)*(m+1) + (m+1) + m] += p1*cm;
        if (m > 0) acc[(m+1)*(m+1) + 1] += p1*sm;
        #pragma unroll
        for (int l=m+2; l<=MAXL; ++l){
          float pn = ((float)(2*l-1)*X*p1 - (float)(l+m-1)*p0) * (1.0f/(float)(l-m));
          p0 = p1; p1 = pn;
          acc[l*l + l + m] += p1*cm;
          if (m > 0) acc[l*l + l - m] += p1*sm;
        }
      }
    }
  }

  __shared__ double red[4][NC];
  int lane = threadIdx.x & 63, wv = threadIdx.x >> 6;
  #pragma unroll
  for (int v=0; v<NC; ++v){
    double d = (double)acc[v];
    for (int off=32; off; off>>=1) d += __shfl_down(d, off);
    if (lane == 0) red[wv][v] = d;
  }
  __syncthreads();
  for (int v = threadIdx.x; v < NC; v += blockDim.x){
    double s = red[0][v] + red[1][v] + red[2][v] + red[3][v];
    unsafeAtomicAdd(gacc + mat*NC + v, s);
  }
}

// ---------------- compress: parallel (81 threads), all state in LDS/regs ----------------
__global__ __launch_bounds__(128) void k_compress(const double* __restrict__ gacc,
                                                  float* __restrict__ cfin){
  const int mat = blockIdx.x;
  const int v = threadIdx.x;
  __shared__ float mg[NC];
  __shared__ float smg2[NC];   // mg^2 scattered into rank order
  __shared__ int cnt_sh;

  float c = 0.0f, m = -1.0f;
  if (v < NC){
    double m_ = (double)g_norm.v[v] * gacc[mat*NC + v] / (double)NPAIR;
    c = (float)m_;
    m = fabsf(c);
    mg[v] = m;
  }
  if (v == 0) cnt_sh = 0;
  __syncthreads();

  int rank = 0;
  if (v < NC){
    #pragma unroll 1
    for (int u = 0; u < NC; ++u){
      float mu = mg[u];
      rank += (mu > m) || (mu == m && u < v);
    }
    smg2[rank] = m*m;
  }
  __syncthreads();

  float e_mine = 0.0f, tot = 0.0f;
  if (v < NC){
    float run = 0.0f;
    #pragma unroll 1
    for (int u = 0; u < NC; ++u){
      run += smg2[u];
      if (u == rank) e_mine = run;
    }
    tot = run;
    float den = fmaxf(tot, 1e-30f);
    if (tot > 0.0f && (e_mine / den <= 0.9999f)) atomicAdd(&cnt_sh, 1);
  }
  __syncthreads();

  if (v < NC){
    int kc = (tot > 0.0f) ? (cnt_sh + 1) : NC;
    if (kc < NC/2) kc = NC/2;   // 40
    float cv = (rank < kc) ? c : 0.0f;
    if (fabsf(cv) <= 1e-10f) cv = 0.0f;   // inverse's |c|>1e-10 mask folded in
    cfin[mat*NC + v] = cv;
  }
}

// ---------------- inverse transform -> compact bf16 B1 (1536x384), B2 (768x1536) ----------------
__global__ __launch_bounds__(256) void k_inverse(const float* __restrict__ cfin,
    const unsigned* __restrict__ scaleBits, __bf16* __restrict__ B1, __bf16* __restrict__ B2){
  __shared__ float cA[NC], cB[NC], sc[2];
  if (threadIdx.x < NC){ cA[threadIdx.x] = cfin[threadIdx.x]; cB[threadIdx.x] = cfin[NC + threadIdx.x]; }
  if (threadIdx.x < 2) sc[threadIdx.x] = __uint_as_float(scaleBits[threadIdx.x]);
  __syncthreads();
  int j = blockIdx.x*blockDim.x + threadIdx.x;
  if (j >= NPAIR) return;

  float jf = (float)j;
  float r = fminf((jf + 0.5f) / 1179648.0f * 0.95f, 0.95f);
  float theta = fmodf((6.28318530717958647692f * jf) * 0.618033988749f, 1.0f);
  float phi = theta;
  float X = cosf(2.0f*atanhf(fminf(r, 0.99f))*PI_F/16.0f);
  float sint = sqrtf(fmaxf(1.0f - X*X, 0.0f));
  float s1, c1; sincosf(phi, &s1, &c1);

  float ra = 0.0f, rb = 0.0f;
  float cm = 1.0f, sm = 0.0f, pmm = 1.0f, fact = 1.0f;

  auto emit = [&](int l, int m, float P){
    int ip = l*l + l + m;
    float y = g_norm.v[ip] * P;
    float yc = y*cm;
    ra += cA[ip]*yc; rb += cB[ip]*yc;
    if (m > 0){
      int in_ = l*l + l - m;
      float ys = y*sm;
      ra += cA[in_]*ys; rb += cB[in_]*ys;
    }
  };

  #pragma unroll
  for (int m=0; m<=MAXL; ++m){
    if (m > 0){
      float t = cm*c1 - sm*s1;
      sm = sm*c1 + cm*s1;
      cm = t;
      pmm = pmm * (-fact*sint);
      fact += 2.0f;
    }
    float p0 = pmm;
    emit(m, m, p0);
    if (m < MAXL){
      float p1 = X*(float)(2*m+1)*p0;
      emit(m+1, m, p1);
      #pragma unroll
      for (int l=m+2; l<=MAXL; ++l){
        float pn = ((float)(2*l-1)*X*p1 - (float)(l+m-1)*p0) * (1.0f/(float)(l-m));
        p0 = p1; p1 = pn;
        emit(l, m, p1);
      }
    }
  }

  float sA = sc[0], sB = sc[1];
  B2[j] = (__bf16)((sB > 0.0f) ? rb*sB : rb);     // W_proj[d][2fc], flat j = d*1536+fc
  int q = j / 768, rem = j - q*768;
  if (rem < 384)                                  // even f rows of W_fc only
    B1[q*384 + rem] = (__bf16)((sA > 0.0f) ? ra*sA : ra); // W_fc[2fr][2dc]
}

// ---------------- gather even columns of x -> bf16 ----------------
__global__ void k_gather(const float* __restrict__ x, __bf16* __restrict__ A1){
  int t = blockIdx.x*blockDim.x + threadIdx.x;
  if (t < 8192*384){
    float2 v = ((const float2*)x)[t];   // x[row][2dc] = .x
    A1[t] = (__bf16)v.x;
  }
}

// ---------------- bf16 MFMA GEMM (NT): C[M,N] = A[M,K] . B[N,K]^T + bias (opt gelu) ----------
// 128x128 tile, BK=32, 4 waves (2x2), 16x16x32 MFMA, global_load_lds staging (m97 structure)
template<int ACT, int OUTBF>
__global__ __launch_bounds__(256) void k_gemm_mfma(
    const __bf16* __restrict__ A, const __bf16* __restrict__ B,
    const float* __restrict__ bias, int bmul, int blen,
    float imp0, float imp1,
    __bf16* __restrict__ Hout, float* __restrict__ Fout,
    int N, int K)
{
  __shared__ __bf16 As[128*32];
  __shared__ __bf16 Bs[128*32];
  const int tid  = threadIdx.x;
  const int wave = tid >> 6, lane = tid & 63;
  const int wr = wave >> 1, wc = wave & 1;
  const int rr = lane & 15, kq = lane >> 4;
  const int bm = blockIdx.y * 128, bn = blockIdx.x * 128;

  const int grow = lane >> 2;          // row within 16-row chunk
  const int gcol = (lane & 3) * 8;     // k offset within 32
  const __bf16* Abase = A + (size_t)bm * K;
  const __bf16* Bbase = B + (size_t)bn * K;

  f32x4 acc[4][4] = {};

  for (int k0 = 0; k0 < K; k0 += 32) {
    #pragma unroll
    for (int is = 0; is < 2; ++is) {
      const int c = is * 4 + wave;     // 8 chunks of 16 rows
      const __bf16* ga = Abase + (size_t)(c*16 + grow) * K + (k0 + gcol);
      const __bf16* gb = Bbase + (size_t)(c*16 + grow) * K + (k0 + gcol);
      __builtin_amdgcn_global_load_lds((glb_void*)ga, (lds_void*)(As + c*512), 16, 0, 0);
      __builtin_amdgcn_global_load_lds((glb_void*)gb, (lds_void*)(Bs + c*512), 16, 0, 0);
    }
    __syncthreads();

    bf16x8 af[4], bfr[4];
    #pragma unroll
    for (int i=0;i<4;++i) af[i]  = *(const bf16x8*)&As[(wr*64 + i*16 + rr)*32 + kq*8];
    #pragma unroll
    for (int j=0;j<4;++j) bfr[j] = *(const bf16x8*)&Bs[(wc*64 + j*16 + rr)*32 + kq*8];
    #pragma unroll
    for (int i=0;i<4;++i)
      #pragma unroll
      for (int j=0;j<4;++j)
        acc[i][j] = __builtin_amdgcn_mfma_f32_16x16x32_bf16(af[i], bfr[j], acc[i][j], 0, 0, 0);
    __syncthreads();
  }

  // epilogue: C/D layout col=lane&15, row=(lane>>4)*4+reg
  #pragma unroll
  for (int j=0;j<4;++j){
    const int col = bn + wc*64 + j*16 + rr;
    const float bb = imp0*bias[bmul*col] + imp1*bias[blen + bmul*col];
    #pragma unroll
    for (int i=0;i<4;++i){
      const int row0 = bm + wr*64 + i*16 + kq*4;
      #pragma unroll
      for (int t=0;t<4;++t){
        float v = acc[i][j][t] + bb;
        if (ACT) v = 0.5f*v*(1.0f + erff(v*0.70710678118654752440f));
        if (OUTBF) Hout[(size_t)(row0+t)*N + col] = (__bf16)v;
        else       Fout[(size_t)(row0+t)*N + col] = v;
      }
    }
  }
}

// ---------------- launch ----------------
extern "C" void kernel_launch(void* const* d_in, const int* in_sizes, int n_in,
                              void* d_out, int out_size, void* d_ws, size_t ws_size,
                              hipStream_t stream){
  const float* x   = (const float*)d_in[0];
  const float* wfc = (const float*)d_in[1];
  const float* wpr = (const float*)d_in[2];
  const float* bfc = (const float*)d_in[3];
  const float* bpr = (const float*)d_in[4];
  float* out = (float*)d_out;

  char* ws = (char*)d_ws;
  size_t off = 0;
  auto alloc = [&](size_t bytes){ void* p = ws + off; off = (off + bytes + 255) & ~(size_t)255; return p; };

  float2* fused      = (float2*)  alloc(2*(size_t)NPAIR*sizeof(float2));
  unsigned* scaleBits= (unsigned*)alloc(8);
  double* gacc       = (double*)  alloc(2*NC*sizeof(double));
  float* cfin        = (float*)   alloc(2*NC*sizeof(float));
  __bf16* B1         = (__bf16*)  alloc((size_t)1536*384*sizeof(__bf16));
  __bf16* B2         = (__bf16*)  alloc((size_t)768*1536*sizeof(__bf16));
  __bf16* A1         = (__bf16*)  alloc((size_t)8192*384*sizeof(__bf16));
  __bf16* H          = (__bf16*)  alloc((size_t)8192*1536*sizeof(__bf16));

  const float imp0 = (float)0.37754066879814546;   // softmax([0,0.5])
  const float imp1 = (float)0.62245933120185454;

  k_init<<<1,256,0,stream>>>(scaleBits, gacc);
  k_fuse_scale<<<dim3(1152,2),256,0,stream>>>(wfc, wpr, fused, scaleBits, imp0, imp1);
  k_coeff<<<dim3(512,2),256,0,stream>>>(fused, scaleBits, gacc);
  k_compress<<<2,128,0,stream>>>(gacc, cfin);
  k_inverse<<<4608,256,0,stream>>>(cfin, scaleBits, B1, B2);
  k_gather<<<12288,256,0,stream>>>(x, A1);
  // GEMM1: H[8192,1536] = gelu(A1 . B1^T + bias_fc[2*col]) in bf16
  k_gemm_mfma<1,1><<<dim3(12,64),256,0,stream>>>(A1, B1, bfc, 2, 3072, imp0, imp1, H, nullptr, 1536, 384);
  // GEMM2: out[8192,768] = H . B2^T + bias_proj[col] in fp32
  k_gemm_mfma<0,0><<<dim3(6,64),256,0,stream>>>(H, B2, bpr, 1, 768, imp0, imp1, nullptr, out, 768, 1536);
}

// Round 4
// 225.849 us; speedup vs baseline: 4.2745x; 1.4299x over previous
//
#include <hip/hip_runtime.h>

#define MAXL 8
#define NC 81              // (MAXL+1)^2
#define NPAIR 1179648      // 3072*768/2
#define TOTW  2359296      // 3072*768
#define PI_F 3.14159265358979323846f

typedef __attribute__((ext_vector_type(8))) __bf16 bf16x8;
typedef __attribute__((ext_vector_type(4))) float f32x4;
typedef __attribute__((address_space(3))) void lds_void;
typedef const __attribute__((address_space(1))) void glb_void;

// ---------------- compile-time norm table ----------------
constexpr double cfact(int n){ double r=1.0; for(int i=2;i<=n;++i) r*=(double)i; return r; }
constexpr double csqrtd(double x){
  double r = (x > 1.0) ? x : 1.0;
  for (int i=0;i<200;++i) r = 0.5*(r + x/r);
  return r;
}
struct Norms { float v[NC]; };
constexpr Norms make_norms(){
  Norms t{};
  for (int l=0;l<=MAXL;++l)
    for (int m=-l;m<=l;++m){
      int am = m<0?-m:m;
      double nn = csqrtd((double)(2*l+1)*cfact(l-am)/cfact(l+am)/(4.0*3.14159265358979323846));
      t.v[l*l+l+m] = (float)nn;
    }
  return t;
}
__constant__ Norms g_norm = make_norms();

// ---------------- init: zero scale + accumulators ----------------
__global__ void k_init(unsigned* scaleBits, double* gacc){
  int t = threadIdx.x;
  if (t < 2) scaleBits[t] = 0u;
  if (t < 2*NC) gacc[t] = 0.0;
}

// ---------------- pass 1: max |fused z| only (no materialization) ----------------
// 128 blocks/mat, per-block LDS reduce -> ONE atomic per block (256 total).
__global__ __launch_bounds__(256) void k_max(const float* __restrict__ wfc,
    const float* __restrict__ wpr, unsigned* __restrict__ scaleBits,
    float imp0, float imp1){
  const int mat = blockIdx.y;
  const float2* w0 = (const float2*)(mat ? wpr : wfc);
  const float2* w1 = w0 + (TOTW/2);
  float vmax = 0.0f;
  for (int i = blockIdx.x*blockDim.x + threadIdx.x; i < NPAIR; i += gridDim.x*blockDim.x){
    float2 a = w0[i], b = w1[i];
    float re = fmaf(imp0, a.x, imp1*b.x);
    float im = fmaf(imp0, a.y, imp1*b.y);
    vmax = fmaxf(vmax, sqrtf(re*re + im*im));
  }
  for (int off=32; off; off>>=1) vmax = fmaxf(vmax, __shfl_down(vmax, off));
  __shared__ float red[4];
  int lane = threadIdx.x & 63, wv = threadIdx.x >> 6;
  if (lane == 0) red[wv] = vmax;
  __syncthreads();
  if (threadIdx.x == 0){
    float m = fmaxf(fmaxf(red[0], red[1]), fmaxf(red[2], red[3]));
    atomicMax(scaleBits + mat, __float_as_uint(m));
  }
}

// ---------------- coeff reduction: fuse + sphere + harmonics in one pass ----------------
__global__ __launch_bounds__(256) void k_coeff(const float* __restrict__ wfc,
                                               const float* __restrict__ wpr,
                                               const unsigned* __restrict__ scaleBits,
                                               double* __restrict__ gacc){
  const int mat = blockIdx.y;
  const float2* w0 = (const float2*)(mat ? wpr : wfc);
  const float2* w1 = w0 + (TOTW/2);
  const float scale = __uint_as_float(scaleBits[mat]);
  const float safe = scale > 0.0f ? scale : 1.0f;
  const bool has = scale > 0.0f;
  const float imp0 = (float)0.37754066879814546;
  const float imp1 = (float)0.62245933120185454;

  float acc[NC];
  #pragma unroll
  for (int v=0; v<NC; ++v) acc[v] = 0.0f;

  for (int i = blockIdx.x*blockDim.x + threadIdx.x; i < NPAIR; i += gridDim.x*blockDim.x){
    float2 av = w0[i], bv = w1[i];
    float re = fmaf(imp0, av.x, imp1*bv.x);
    float im = fmaf(imp0, av.y, imp1*bv.y);
    float pr, pi_;
    if (has){
      float a = re/safe, b = im/safe;
      float den = coshf(2.0f*a) + cosf(2.0f*b);
      pr  = sinhf(2.0f*a)/den*0.95f;
      pi_ = sinf(2.0f*b)/den*0.95f;
    } else { pr = re; pi_ = im; }
    float r = sqrtf(pr*pr + pi_*pi_);
    float phi = atan2f(pi_, pr);
    float X = cosf(2.0f*atanhf(fminf(r,0.99f))*PI_F/16.0f);

    float sint = sqrtf(fmaxf(1.0f - X*X, 0.0f));
    float s1, c1; sincosf(phi, &s1, &c1);
    float cm = 1.0f, sm = 0.0f, pmm = 1.0f, fact = 1.0f;
    #pragma unroll
    for (int m=0; m<=MAXL; ++m){
      if (m > 0){
        float t = cm*c1 - sm*s1;
        sm = sm*c1 + cm*s1;
        cm = t;
        pmm = pmm * (-fact*sint);
        fact += 2.0f;
      }
      float p0 = pmm;
      acc[m*m + 2*m] += p0*cm;
      if (m > 0) acc[m*m] += p0*sm;
      if (m < MAXL){
        float p1 = X*(float)(2*m+1)*p0;
        acc[(m+1)*(m+1) + (m+1) + m] += p1*cm;
        if (m > 0) acc[(m+1)*(m+1) + 1] += p1*sm;
        #pragma unroll
        for (int l=m+2; l<=MAXL; ++l){
          float pn = ((float)(2*l-1)*X*p1 - (float)(l+m-1)*p0) * (1.0f/(float)(l-m));
          p0 = p1; p1 = pn;
          acc[l*l + l + m] += p1*cm;
          if (m > 0) acc[l*l + l - m] += p1*sm;
        }
      }
    }
  }

  __shared__ double red[4][NC];
  int lane = threadIdx.x & 63, wv = threadIdx.x >> 6;
  #pragma unroll
  for (int v=0; v<NC; ++v){
    double d = (double)acc[v];
    for (int off=32; off; off>>=1) d += __shfl_down(d, off);
    if (lane == 0) red[wv][v] = d;
  }
  __syncthreads();
  for (int v = threadIdx.x; v < NC; v += blockDim.x){
    double s = red[0][v] + red[1][v] + red[2][v] + red[3][v];
    unsafeAtomicAdd(gacc + mat*NC + v, s);
  }
}

// ---------------- compress: parallel (81 threads), all state in LDS/regs ----------------
__global__ __launch_bounds__(128) void k_compress(const double* __restrict__ gacc,
                                                  float* __restrict__ cfin){
  const int mat = blockIdx.x;
  const int v = threadIdx.x;
  __shared__ float mg[NC];
  __shared__ float smg2[NC];   // mg^2 scattered into rank order
  __shared__ int cnt_sh;

  float c = 0.0f, m = -1.0f;
  if (v < NC){
    double m_ = (double)g_norm.v[v] * gacc[mat*NC + v] / (double)NPAIR;
    c = (float)m_;
    m = fabsf(c);
    mg[v] = m;
  }
  if (v == 0) cnt_sh = 0;
  __syncthreads();

  int rank = 0;
  if (v < NC){
    #pragma unroll 1
    for (int u = 0; u < NC; ++u){
      float mu = mg[u];
      rank += (mu > m) || (mu == m && u < v);
    }
    smg2[rank] = m*m;
  }
  __syncthreads();

  float e_mine = 0.0f, tot = 0.0f;
  if (v < NC){
    float run = 0.0f;
    #pragma unroll 1
    for (int u = 0; u < NC; ++u){
      run += smg2[u];
      if (u == rank) e_mine = run;
    }
    tot = run;
    float den = fmaxf(tot, 1e-30f);
    if (tot > 0.0f && (e_mine / den <= 0.9999f)) atomicAdd(&cnt_sh, 1);
  }
  __syncthreads();

  if (v < NC){
    int kc = (tot > 0.0f) ? (cnt_sh + 1) : NC;
    if (kc < NC/2) kc = NC/2;   // 40
    float cv = (rank < kc) ? c : 0.0f;
    if (fabsf(cv) <= 1e-10f) cv = 0.0f;   // inverse's |c|>1e-10 mask folded in
    cfin[mat*NC + v] = cv;
  }
}

// ---------------- inverse transform -> compact bf16 B1 (1536x384), B2 (768x1536) ----------------
__global__ __launch_bounds__(256) void k_inverse(const float* __restrict__ cfin,
    const unsigned* __restrict__ scaleBits, __bf16* __restrict__ B1, __bf16* __restrict__ B2){
  __shared__ float cA[NC], cB[NC], sc[2];
  if (threadIdx.x < NC){ cA[threadIdx.x] = cfin[threadIdx.x]; cB[threadIdx.x] = cfin[NC + threadIdx.x]; }
  if (threadIdx.x < 2) sc[threadIdx.x] = __uint_as_float(scaleBits[threadIdx.x]);
  __syncthreads();
  int j = blockIdx.x*blockDim.x + threadIdx.x;
  if (j >= NPAIR) return;

  float jf = (float)j;
  float r = fminf((jf + 0.5f) / 1179648.0f * 0.95f, 0.95f);
  float theta = fmodf((6.28318530717958647692f * jf) * 0.618033988749f, 1.0f);
  float phi = theta;
  float X = cosf(2.0f*atanhf(fminf(r, 0.99f))*PI_F/16.0f);
  float sint = sqrtf(fmaxf(1.0f - X*X, 0.0f));
  float s1, c1; sincosf(phi, &s1, &c1);

  float ra = 0.0f, rb = 0.0f;
  float cm = 1.0f, sm = 0.0f, pmm = 1.0f, fact = 1.0f;

  auto emit = [&](int l, int m, float P){
    int ip = l*l + l + m;
    float y = g_norm.v[ip] * P;
    float yc = y*cm;
    ra += cA[ip]*yc; rb += cB[ip]*yc;
    if (m > 0){
      int in_ = l*l + l - m;
      float ys = y*sm;
      ra += cA[in_]*ys; rb += cB[in_]*ys;
    }
  };

  #pragma unroll
  for (int m=0; m<=MAXL; ++m){
    if (m > 0){
      float t = cm*c1 - sm*s1;
      sm = sm*c1 + cm*s1;
      cm = t;
      pmm = pmm * (-fact*sint);
      fact += 2.0f;
    }
    float p0 = pmm;
    emit(m, m, p0);
    if (m < MAXL){
      float p1 = X*(float)(2*m+1)*p0;
      emit(m+1, m, p1);
      #pragma unroll
      for (int l=m+2; l<=MAXL; ++l){
        float pn = ((float)(2*l-1)*X*p1 - (float)(l+m-1)*p0) * (1.0f/(float)(l-m));
        p0 = p1; p1 = pn;
        emit(l, m, p1);
      }
    }
  }

  float sA = sc[0], sB = sc[1];
  B2[j] = (__bf16)((sB > 0.0f) ? rb*sB : rb);     // W_proj[d][2fc], flat j = d*1536+fc
  int q = j / 768, rem = j - q*768;
  if (rem < 384)                                  // even f rows of W_fc only
    B1[q*384 + rem] = (__bf16)((sA > 0.0f) ? ra*sA : ra); // W_fc[2fr][2dc]
}

// ---------------- gather even columns of x -> bf16 ----------------
__global__ void k_gather(const float* __restrict__ x, __bf16* __restrict__ A1){
  int t = blockIdx.x*blockDim.x + threadIdx.x;
  if (t < 8192*384){
    float2 v = ((const float2*)x)[t];   // x[row][2dc] = .x
    A1[t] = (__bf16)v.x;
  }
}

// ---------------- bf16 MFMA GEMM (NT): C[M,N] = A[M,K] . B[N,K]^T + bias (opt gelu) ----------
// 128x128 tile, BK=32, 4 waves (2x2), 16x16x32 MFMA, global_load_lds staging (m97 structure)
template<int ACT, int OUTBF>
__global__ __launch_bounds__(256) void k_gemm_mfma(
    const __bf16* __restrict__ A, const __bf16* __restrict__ B,
    const float* __restrict__ bias, int bmul, int blen,
    float imp0, float imp1,
    __bf16* __restrict__ Hout, float* __restrict__ Fout,
    int N, int K)
{
  __shared__ __bf16 As[128*32];
  __shared__ __bf16 Bs[128*32];
  const int tid  = threadIdx.x;
  const int wave = tid >> 6, lane = tid & 63;
  const int wr = wave >> 1, wc = wave & 1;
  const int rr = lane & 15, kq = lane >> 4;
  const int bm = blockIdx.y * 128, bn = blockIdx.x * 128;

  const int grow = lane >> 2;          // row within 16-row chunk
  const int gcol = (lane & 3) * 8;     // k offset within 32
  const __bf16* Abase = A + (size_t)bm * K;
  const __bf16* Bbase = B + (size_t)bn * K;

  f32x4 acc[4][4] = {};

  for (int k0 = 0; k0 < K; k0 += 32) {
    #pragma unroll
    for (int is = 0; is < 2; ++is) {
      const int c = is * 4 + wave;     // 8 chunks of 16 rows
      const __bf16* ga = Abase + (size_t)(c*16 + grow) * K + (k0 + gcol);
      const __bf16* gb = Bbase + (size_t)(c*16 + grow) * K + (k0 + gcol);
      __builtin_amdgcn_global_load_lds((glb_void*)ga, (lds_void*)(As + c*512), 16, 0, 0);
      __builtin_amdgcn_global_load_lds((glb_void*)gb, (lds_void*)(Bs + c*512), 16, 0, 0);
    }
    __syncthreads();

    bf16x8 af[4], bfr[4];
    #pragma unroll
    for (int i=0;i<4;++i) af[i]  = *(const bf16x8*)&As[(wr*64 + i*16 + rr)*32 + kq*8];
    #pragma unroll
    for (int j=0;j<4;++j) bfr[j] = *(const bf16x8*)&Bs[(wc*64 + j*16 + rr)*32 + kq*8];
    #pragma unroll
    for (int i=0;i<4;++i)
      #pragma unroll
      for (int j=0;j<4;++j)
        acc[i][j] = __builtin_amdgcn_mfma_f32_16x16x32_bf16(af[i], bfr[j], acc[i][j], 0, 0, 0);
    __syncthreads();
  }

  // epilogue: C/D layout col=lane&15, row=(lane>>4)*4+reg
  #pragma unroll
  for (int j=0;j<4;++j){
    const int col = bn + wc*64 + j*16 + rr;
    const float bb = imp0*bias[bmul*col] + imp1*bias[blen + bmul*col];
    #pragma unroll
    for (int i=0;i<4;++i){
      const int row0 = bm + wr*64 + i*16 + kq*4;
      #pragma unroll
      for (int t=0;t<4;++t){
        float v = acc[i][j][t] + bb;
        if (ACT) v = 0.5f*v*(1.0f + erff(v*0.70710678118654752440f));
        if (OUTBF) Hout[(size_t)(row0+t)*N + col] = (__bf16)v;
        else       Fout[(size_t)(row0+t)*N + col] = v;
      }
    }
  }
}

// ---------------- launch ----------------
extern "C" void kernel_launch(void* const* d_in, const int* in_sizes, int n_in,
                              void* d_out, int out_size, void* d_ws, size_t ws_size,
                              hipStream_t stream){
  const float* x   = (const float*)d_in[0];
  const float* wfc = (const float*)d_in[1];
  const float* wpr = (const float*)d_in[2];
  const float* bfc = (const float*)d_in[3];
  const float* bpr = (const float*)d_in[4];
  float* out = (float*)d_out;

  char* ws = (char*)d_ws;
  size_t off = 0;
  auto alloc = [&](size_t bytes){ void* p = ws + off; off = (off + bytes + 255) & ~(size_t)255; return p; };

  unsigned* scaleBits= (unsigned*)alloc(8);
  double* gacc       = (double*)  alloc(2*NC*sizeof(double));
  float* cfin        = (float*)   alloc(2*NC*sizeof(float));
  __bf16* B1         = (__bf16*)  alloc((size_t)1536*384*sizeof(__bf16));
  __bf16* B2         = (__bf16*)  alloc((size_t)768*1536*sizeof(__bf16));
  __bf16* A1         = (__bf16*)  alloc((size_t)8192*384*sizeof(__bf16));
  __bf16* H          = (__bf16*)  alloc((size_t)8192*1536*sizeof(__bf16));

  const float imp0 = (float)0.37754066879814546;   // softmax([0,0.5])
  const float imp1 = (float)0.62245933120185454;

  k_init<<<1,256,0,stream>>>(scaleBits, gacc);
  k_max<<<dim3(128,2),256,0,stream>>>(wfc, wpr, scaleBits, imp0, imp1);
  k_coeff<<<dim3(512,2),256,0,stream>>>(wfc, wpr, scaleBits, gacc);
  k_compress<<<2,128,0,stream>>>(gacc, cfin);
  k_inverse<<<4608,256,0,stream>>>(cfin, scaleBits, B1, B2);
  k_gather<<<12288,256,0,stream>>>(x, A1);
  // GEMM1: H[8192,1536] = gelu(A1 . B1^T + bias_fc[2*col]) in bf16
  k_gemm_mfma<1,1><<<dim3(12,64),256,0,stream>>>(A1, B1, bfc, 2, 3072, imp0, imp1, H, nullptr, 1536, 384);
  // GEMM2: out[8192,768] = H . B2^T + bias_proj[col] in fp32
  k_gemm_mfma<0,0><<<dim3(6,64),256,0,stream>>>(H, B2, bpr, 1, 768, imp0, imp1, nullptr, out, 768, 1536);
}

// Round 5
// 207.001 us; speedup vs baseline: 4.6637x; 1.0911x over previous
//
#include <hip/hip_runtime.h>

#define MAXL 8
#define NC 81              // (MAXL+1)^2
#define NPAIR 1179648      // 3072*768/2
#define TOTW  2359296      // 3072*768
#define PI_F 3.14159265358979323846f

typedef __attribute__((ext_vector_type(8))) __bf16 bf16x8;
typedef __attribute__((ext_vector_type(4))) float f32x4;
typedef __attribute__((address_space(3))) void lds_void;
typedef const __attribute__((address_space(1))) void glb_void;

// ---------------- compile-time norm table ----------------
constexpr double cfact(int n){ double r=1.0; for(int i=2;i<=n;++i) r*=(double)i; return r; }
constexpr double csqrtd(double x){
  double r = (x > 1.0) ? x : 1.0;
  for (int i=0;i<200;++i) r = 0.5*(r + x/r);
  return r;
}
struct Norms { float v[NC]; };
constexpr Norms make_norms(){
  Norms t{};
  for (int l=0;l<=MAXL;++l)
    for (int m=-l;m<=l;++m){
      int am = m<0?-m:m;
      double nn = csqrtd((double)(2*l+1)*cfact(l-am)/cfact(l+am)/(4.0*3.14159265358979323846));
      t.v[l*l+l+m] = (float)nn;
    }
  return t;
}
__constant__ Norms g_norm = make_norms();

__device__ __forceinline__ float fast_atanh(float x){
  // 0.5*ln((1+x)/(1-x)) via v_log + v_rcp; |x|<=0.99
  return 0.5f * __logf((1.0f + x) * __builtin_amdgcn_rcpf(1.0f - x));
}

// ---------------- init: zero scale + accumulators ----------------
__global__ void k_init(unsigned* scaleBits, double* gacc){
  int t = threadIdx.x;
  if (t < 2) scaleBits[t] = 0u;
  if (t < 2*NC) gacc[t] = 0.0;
}

// ---------------- pass 1: max |fused z| only ----------------
__global__ __launch_bounds__(256) void k_max(const float* __restrict__ wfc,
    const float* __restrict__ wpr, unsigned* __restrict__ scaleBits,
    float imp0, float imp1){
  const int mat = blockIdx.y;
  const float2* w0 = (const float2*)(mat ? wpr : wfc);
  const float2* w1 = w0 + (TOTW/2);
  float vmax = 0.0f;
  for (int i = blockIdx.x*blockDim.x + threadIdx.x; i < NPAIR; i += gridDim.x*blockDim.x){
    float2 a = w0[i], b = w1[i];
    float re = fmaf(imp0, a.x, imp1*b.x);
    float im = fmaf(imp0, a.y, imp1*b.y);
    vmax = fmaxf(vmax, sqrtf(re*re + im*im));
  }
  for (int off=32; off; off>>=1) vmax = fmaxf(vmax, __shfl_down(vmax, off));
  __shared__ float red[4];
  int lane = threadIdx.x & 63, wv = threadIdx.x >> 6;
  if (lane == 0) red[wv] = vmax;
  __syncthreads();
  if (threadIdx.x == 0){
    float m = fmaxf(fmaxf(red[0], red[1]), fmaxf(red[2], red[3]));
    atomicMax(scaleBits + mat, __float_as_uint(m));
  }
}

// ---------------- coeff reduction: fuse + sphere + harmonics, fast-math mapping ----------------
__global__ __launch_bounds__(256) void k_coeff(const float* __restrict__ wfc,
                                               const float* __restrict__ wpr,
                                               const unsigned* __restrict__ scaleBits,
                                               double* __restrict__ gacc){
  const int mat = blockIdx.y;
  const float2* w0 = (const float2*)(mat ? wpr : wfc);
  const float2* w1 = w0 + (TOTW/2);
  const float scale = __uint_as_float(scaleBits[mat]);
  const bool has = scale > 0.0f;
  const float inv_safe = 1.0f / (has ? scale : 1.0f);
  const float imp0 = (float)0.37754066879814546;
  const float imp1 = (float)0.62245933120185454;

  float acc[NC];
  #pragma unroll
  for (int v=0; v<NC; ++v) acc[v] = 0.0f;

  for (int i = blockIdx.x*blockDim.x + threadIdx.x; i < NPAIR; i += gridDim.x*blockDim.x){
    float2 av = w0[i], bv = w1[i];
    float re = fmaf(imp0, av.x, imp1*bv.x);
    float im = fmaf(imp0, av.y, imp1*bv.y);
    float pr, pi_;
    if (has){
      float a = re*inv_safe, b = im*inv_safe;      // |a|,|b| <= 1
      float e  = __expf(2.0f*a);                   // cosh/sinh from one exp
      float ie = __builtin_amdgcn_rcpf(e);
      float ch = 0.5f*(e + ie), sh = 0.5f*(e - ie);
      float s2b, c2b; __sincosf(2.0f*b, &s2b, &c2b);   // |2b| <= 2 rad
      float inv_den = __builtin_amdgcn_rcpf(ch + c2b); // den >= 0.58
      pr  = sh*inv_den*0.95f;
      pi_ = s2b*inv_den*0.95f;
    } else { pr = re; pi_ = im; }

    // cos/sin(atan2(pi_,pr)) = pr/r, pi_/r  -- no atan2, no sincos
    float r2 = pr*pr + pi_*pi_;
    float inv_r = (r2 > 0.0f) ? __builtin_amdgcn_rsqf(r2) : 0.0f;
    float c1 = (r2 > 0.0f) ? pr*inv_r : 1.0f;
    float s1 = pi_*inv_r;
    float rr_ = r2*inv_r;                          // sqrt(r2)
    float X = __cosf(fast_atanh(fminf(rr_, 0.99f)) * (PI_F/8.0f));
    float sint = sqrtf(fmaxf(1.0f - X*X, 0.0f));

    float cm = 1.0f, sm = 0.0f, pmm = 1.0f, fact = 1.0f;
    #pragma unroll
    for (int m=0; m<=MAXL; ++m){
      if (m > 0){
        float t = cm*c1 - sm*s1;
        sm = sm*c1 + cm*s1;
        cm = t;
        pmm = pmm * (-fact*sint);
        fact += 2.0f;
      }
      float p0 = pmm;
      acc[m*m + 2*m] += p0*cm;
      if (m > 0) acc[m*m] += p0*sm;
      if (m < MAXL){
        float p1 = X*(float)(2*m+1)*p0;
        acc[(m+1)*(m+1) + (m+1) + m] += p1*cm;
        if (m > 0) acc[(m+1)*(m+1) + 1] += p1*sm;
        #pragma unroll
        for (int l=m+2; l<=MAXL; ++l){
          float pn = ((float)(2*l-1)*X*p1 - (float)(l+m-1)*p0) * (1.0f/(float)(l-m));
          p0 = p1; p1 = pn;
          acc[l*l + l + m] += p1*cm;
          if (m > 0) acc[l*l + l - m] += p1*sm;
        }
      }
    }
  }

  __shared__ double red[4][NC];
  int lane = threadIdx.x & 63, wv = threadIdx.x >> 6;
  #pragma unroll
  for (int v=0; v<NC; ++v){
    double d = (double)acc[v];
    for (int off=32; off; off>>=1) d += __shfl_down(d, off);
    if (lane == 0) red[wv][v] = d;
  }
  __syncthreads();
  for (int v = threadIdx.x; v < NC; v += blockDim.x){
    double s = red[0][v] + red[1][v] + red[2][v] + red[3][v];
    unsafeAtomicAdd(gacc + mat*NC + v, s);
  }
}

// ---------------- compress: parallel (81 threads), all state in LDS/regs ----------------
__global__ __launch_bounds__(128) void k_compress(const double* __restrict__ gacc,
                                                  float* __restrict__ cfin){
  const int mat = blockIdx.x;
  const int v = threadIdx.x;
  __shared__ float mg[NC];
  __shared__ float smg2[NC];   // mg^2 scattered into rank order
  __shared__ int cnt_sh;

  float c = 0.0f, m = -1.0f;
  if (v < NC){
    double m_ = (double)g_norm.v[v] * gacc[mat*NC + v] / (double)NPAIR;
    c = (float)m_;
    m = fabsf(c);
    mg[v] = m;
  }
  if (v == 0) cnt_sh = 0;
  __syncthreads();

  int rank = 0;
  if (v < NC){
    #pragma unroll 1
    for (int u = 0; u < NC; ++u){
      float mu = mg[u];
      rank += (mu > m) || (mu == m && u < v);
    }
    smg2[rank] = m*m;
  }
  __syncthreads();

  float e_mine = 0.0f, tot = 0.0f;
  if (v < NC){
    float run = 0.0f;
    #pragma unroll 1
    for (int u = 0; u < NC; ++u){
      run += smg2[u];
      if (u == rank) e_mine = run;
    }
    tot = run;
    float den = fmaxf(tot, 1e-30f);
    if (tot > 0.0f && (e_mine / den <= 0.9999f)) atomicAdd(&cnt_sh, 1);
  }
  __syncthreads();

  if (v < NC){
    int kc = (tot > 0.0f) ? (cnt_sh + 1) : NC;
    if (kc < NC/2) kc = NC/2;   // 40
    float cv = (rank < kc) ? c : 0.0f;
    if (fabsf(cv) <= 1e-10f) cv = 0.0f;   // inverse's |c|>1e-10 mask folded in
    cfin[mat*NC + v] = cv;
  }
}

// ---------------- inverse transform -> compact bf16 B1 (1536x384), B2 (768x1536) ----------------
__global__ __launch_bounds__(256) void k_inverse(const float* __restrict__ cfin,
    const unsigned* __restrict__ scaleBits, __bf16* __restrict__ B1, __bf16* __restrict__ B2){
  __shared__ float cA[NC], cB[NC], sc[2];
  if (threadIdx.x < NC){ cA[threadIdx.x] = cfin[threadIdx.x]; cB[threadIdx.x] = cfin[NC + threadIdx.x]; }
  if (threadIdx.x < 2) sc[threadIdx.x] = __uint_as_float(scaleBits[threadIdx.x]);
  __syncthreads();
  int j = blockIdx.x*blockDim.x + threadIdx.x;
  if (j >= NPAIR) return;

  float jf = (float)j;
  float r = fminf((jf + 0.5f) / 1179648.0f * 0.95f, 0.95f);
  float theta = fmodf((6.28318530717958647692f * jf) * 0.618033988749f, 1.0f);
  float phi = theta;
  float X = __cosf(fast_atanh(fminf(r, 0.99f)) * (PI_F/8.0f));
  float sint = sqrtf(fmaxf(1.0f - X*X, 0.0f));
  float s1, c1; __sincosf(phi, &s1, &c1);   // phi in [0,1)

  float ra = 0.0f, rb = 0.0f;
  float cm = 1.0f, sm = 0.0f, pmm = 1.0f, fact = 1.0f;

  auto emit = [&](int l, int m, float P){
    int ip = l*l + l + m;
    float y = g_norm.v[ip] * P;
    float yc = y*cm;
    ra += cA[ip]*yc; rb += cB[ip]*yc;
    if (m > 0){
      int in_ = l*l + l - m;
      float ys = y*sm;
      ra += cA[in_]*ys; rb += cB[in_]*ys;
    }
  };

  #pragma unroll
  for (int m=0; m<=MAXL; ++m){
    if (m > 0){
      float t = cm*c1 - sm*s1;
      sm = sm*c1 + cm*s1;
      cm = t;
      pmm = pmm * (-fact*sint);
      fact += 2.0f;
    }
    float p0 = pmm;
    emit(m, m, p0);
    if (m < MAXL){
      float p1 = X*(float)(2*m+1)*p0;
      emit(m+1, m, p1);
      #pragma unroll
      for (int l=m+2; l<=MAXL; ++l){
        float pn = ((float)(2*l-1)*X*p1 - (float)(l+m-1)*p0) * (1.0f/(float)(l-m));
        p0 = p1; p1 = pn;
        emit(l, m, p1);
      }
    }
  }

  float sA = sc[0], sB = sc[1];
  B2[j] = (__bf16)((sB > 0.0f) ? rb*sB : rb);     // W_proj[d][2fc], flat j = d*1536+fc
  int q = j / 768, rem = j - q*768;
  if (rem < 384)                                  // even f rows of W_fc only
    B1[q*384 + rem] = (__bf16)((sA > 0.0f) ? ra*sA : ra); // W_fc[2fr][2dc]
}

// ---------------- gather even columns of x -> bf16 ----------------
__global__ void k_gather(const float* __restrict__ x, __bf16* __restrict__ A1){
  int t = blockIdx.x*blockDim.x + threadIdx.x;
  if (t < 8192*384){
    float2 v = ((const float2*)x)[t];   // x[row][2dc] = .x
    A1[t] = (__bf16)v.x;
  }
}

// ---------------- bf16 MFMA GEMM (NT): C[M,N] = A[M,K] . B[N,K]^T + bias (opt gelu) ----------
template<int ACT, int OUTBF>
__global__ __launch_bounds__(256) void k_gemm_mfma(
    const __bf16* __restrict__ A, const __bf16* __restrict__ B,
    const float* __restrict__ bias, int bmul, int blen,
    float imp0, float imp1,
    __bf16* __restrict__ Hout, float* __restrict__ Fout,
    int N, int K)
{
  __shared__ __bf16 As[128*32];
  __shared__ __bf16 Bs[128*32];
  const int tid  = threadIdx.x;
  const int wave = tid >> 6, lane = tid & 63;
  const int wr = wave >> 1, wc = wave & 1;
  const int rr = lane & 15, kq = lane >> 4;
  const int bm = blockIdx.y * 128, bn = blockIdx.x * 128;

  const int grow = lane >> 2;          // row within 16-row chunk
  const int gcol = (lane & 3) * 8;     // k offset within 32
  const __bf16* Abase = A + (size_t)bm * K;
  const __bf16* Bbase = B + (size_t)bn * K;

  f32x4 acc[4][4] = {};

  for (int k0 = 0; k0 < K; k0 += 32) {
    #pragma unroll
    for (int is = 0; is < 2; ++is) {
      const int c = is * 4 + wave;     // 8 chunks of 16 rows
      const __bf16* ga = Abase + (size_t)(c*16 + grow) * K + (k0 + gcol);
      const __bf16* gb = Bbase + (size_t)(c*16 + grow) * K + (k0 + gcol);
      __builtin_amdgcn_global_load_lds((glb_void*)ga, (lds_void*)(As + c*512), 16, 0, 0);
      __builtin_amdgcn_global_load_lds((glb_void*)gb, (lds_void*)(Bs + c*512), 16, 0, 0);
    }
    __syncthreads();

    bf16x8 af[4], bfr[4];
    #pragma unroll
    for (int i=0;i<4;++i) af[i]  = *(const bf16x8*)&As[(wr*64 + i*16 + rr)*32 + kq*8];
    #pragma unroll
    for (int j=0;j<4;++j) bfr[j] = *(const bf16x8*)&Bs[(wc*64 + j*16 + rr)*32 + kq*8];
    #pragma unroll
    for (int i=0;i<4;++i)
      #pragma unroll
      for (int j=0;j<4;++j)
        acc[i][j] = __builtin_amdgcn_mfma_f32_16x16x32_bf16(af[i], bfr[j], acc[i][j], 0, 0, 0);
    __syncthreads();
  }

  // epilogue: C/D layout col=lane&15, row=(lane>>4)*4+reg
  #pragma unroll
  for (int j=0;j<4;++j){
    const int col = bn + wc*64 + j*16 + rr;
    const float bb = imp0*bias[bmul*col] + imp1*bias[blen + bmul*col];
    #pragma unroll
    for (int i=0;i<4;++i){
      const int row0 = bm + wr*64 + i*16 + kq*4;
      #pragma unroll
      for (int t=0;t<4;++t){
        float v = acc[i][j][t] + bb;
        if (ACT) v = 0.5f*v*(1.0f + erff(v*0.70710678118654752440f));
        if (OUTBF) Hout[(size_t)(row0+t)*N + col] = (__bf16)v;
        else       Fout[(size_t)(row0+t)*N + col] = v;
      }
    }
  }
}

// ---------------- launch ----------------
extern "C" void kernel_launch(void* const* d_in, const int* in_sizes, int n_in,
                              void* d_out, int out_size, void* d_ws, size_t ws_size,
                              hipStream_t stream){
  const float* x   = (const float*)d_in[0];
  const float* wfc = (const float*)d_in[1];
  const float* wpr = (const float*)d_in[2];
  const float* bfc = (const float*)d_in[3];
  const float* bpr = (const float*)d_in[4];
  float* out = (float*)d_out;

  char* ws = (char*)d_ws;
  size_t off = 0;
  auto alloc = [&](size_t bytes){ void* p = ws + off; off = (off + bytes + 255) & ~(size_t)255; return p; };

  unsigned* scaleBits= (unsigned*)alloc(8);
  double* gacc       = (double*)  alloc(2*NC*sizeof(double));
  float* cfin        = (float*)   alloc(2*NC*sizeof(float));
  __bf16* B1         = (__bf16*)  alloc((size_t)1536*384*sizeof(__bf16));
  __bf16* B2         = (__bf16*)  alloc((size_t)768*1536*sizeof(__bf16));
  __bf16* A1         = (__bf16*)  alloc((size_t)8192*384*sizeof(__bf16));
  __bf16* H          = (__bf16*)  alloc((size_t)8192*1536*sizeof(__bf16));

  const float imp0 = (float)0.37754066879814546;   // softmax([0,0.5])
  const float imp1 = (float)0.62245933120185454;

  k_init<<<1,256,0,stream>>>(scaleBits, gacc);
  k_max<<<dim3(128,2),256,0,stream>>>(wfc, wpr, scaleBits, imp0, imp1);
  k_coeff<<<dim3(512,2),256,0,stream>>>(wfc, wpr, scaleBits, gacc);
  k_compress<<<2,128,0,stream>>>(gacc, cfin);
  k_inverse<<<4608,256,0,stream>>>(cfin, scaleBits, B1, B2);
  k_gather<<<12288,256,0,stream>>>(x, A1);
  // GEMM1: H[8192,1536] = gelu(A1 . B1^T + bias_fc[2*col]) in bf16
  k_gemm_mfma<1,1><<<dim3(12,64),256,0,stream>>>(A1, B1, bfc, 2, 3072, imp0, imp1, H, nullptr, 1536, 384);
  // GEMM2: out[8192,768] = H . B2^T + bias_proj[col] in fp32
  k_gemm_mfma<0,0><<<dim3(6,64),256,0,stream>>>(H, B2, bpr, 1, 768, imp0, imp1, nullptr, out, 768, 1536);
}